// Round 13
// baseline (481.885 us; speedup 1.0000x reference)
//
#include <hip/hip_runtime.h>
#include <math.h>

#define CONVD 192
#define NC 128
#define PW 32
#define LOG2E 1.4426950408889634f
#define LN2f  0.69314718055994531f

// per-dir workspace offsets (floats)
#define OFF_DST   0u          // Dst  [8*16][128][256]  (delta -> Sin after scan)
#define OFF_CHA   4194304u    // chA  [8*16][128]
#define OFF_YS    4210688u    // ys   [8][8192][16]
#define OFF_PART  5259264u    // partials [1024][32]
#define OFF_TILE  5267456u    // tiles [8*128][6144]
#define PD        11558912u   // floats per dir region (~46 MB)

// tile sub-offsets (floats within a block's 6144-float tile)
#define TG  0        // G blocked per (t4,x4) tile [256][16]
#define TDT 4096     // dt [16][64]
#define TCT 5120     // ct2 [16][64]

// XOR-quad swizzle for [64][64] LDS tiles, element (row m, col t)
#define XSW(m, t)   ((m) * 64 + (((((t) >> 2) ^ ((m) & 15)) & 15) << 2) + ((t) & 3))
#define XSW4(m, tq) ((m) * 64 + ((((tq) ^ ((m) & 15)) & 15) << 2))

typedef float f32x2 __attribute__((ext_vector_type(2)));

__device__ __forceinline__ f32x2 pk_fma(f32x2 a, f32x2 b, f32x2 c) {
    f32x2 d;
    asm("v_pk_fma_f32 %0, %1, %2, %3" : "=v"(d) : "v"(a), "v"(b), "v"(c));
    return d;
}
__device__ __forceinline__ f32x2 lo2(float4 v) { f32x2 r; r.x = v.x; r.y = v.y; return r; }
__device__ __forceinline__ f32x2 hi2(float4 v) { f32x2 r; r.x = v.z; r.y = v.w; return r; }

__device__ __forceinline__ float fast_silu(float x) {
    float e = __builtin_amdgcn_exp2f(-x * LOG2E);
    return x * __builtin_amdgcn_rcpf(1.f + e);
}
__device__ __forceinline__ float fast_softplus(float x) {
    if (x > 20.f) return x;
    float e = __builtin_amdgcn_exp2f(x * LOG2E);
    return LN2f * __builtin_amdgcn_logf(1.f + e);
}

// stage u rows [pos][c] (67 x 16, pad 17) with 3-halo, zeros for l<0
template<int NT>
__device__ __forceinline__ void stage_u(
    const float* __restrict__ x, float* u_s, int b, int l0, int dir, int tid)
{
    for (int i = tid; i < 67 * 16; i += NT) {
        int pos = i >> 4, c = i & 15;
        int l = l0 + pos - 3;
        float v = 0.f;
        if (l >= 0) {
            if (dir == 0) {
                v = x[(b * 16 + c) * 8192 + l];
            } else if (dir == 1) {
                int h = l >> 9, w = (l >> 5) & 15, d = l & 31;
                v = x[(((b * 16 + c) * 32 + d) * 16 + h) * 16 + w];
            } else {
                int w = l >> 9, d = (l >> 4) & 31, h = l & 15;
                v = x[(((b * 16 + c) * 32 + d) * 16 + h) * 16 + w];
            }
        }
        u_s[pos * 17 + c] = v;
    }
}

// packed dot(u2[8], 16-float weight row)
__device__ __forceinline__ float pk_dot16(const f32x2* u2, const float* wp) {
    float4 w0 = *(const float4*)(wp);
    float4 w1 = *(const float4*)(wp + 4);
    float4 w2 = *(const float4*)(wp + 8);
    float4 w3 = *(const float4*)(wp + 12);
    f32x2 a = {0.f, 0.f};
    a = pk_fma(u2[0], lo2(w0), a);
    a = pk_fma(u2[1], hi2(w0), a);
    a = pk_fma(u2[2], lo2(w1), a);
    a = pk_fma(u2[3], hi2(w1), a);
    a = pk_fma(u2[4], lo2(w2), a);
    a = pk_fma(u2[5], hi2(w2), a);
    a = pk_fma(u2[6], lo2(w3), a);
    a = pk_fma(u2[7], hi2(w3), a);
    return a.x + a.y;
}

// ---------------------------------------------------------------------------
// K_FRONT: proj cols 64..271 + conv + silu + scan; dumps ONLY dt, ct2, G to
// the global tile; threads 0-255 compute the Dst delta while threads 256-511
// compute G = C.B^T from LDS. grid (128 ck, 8 b, nz), 512 threads, 62 KB LDS.
// ---------------------------------------------------------------------------
__global__ __launch_bounds__(512, 4) void k_front(
    const float* __restrict__ x, const float* __restrict__ Win,
    const float* __restrict__ convw, const float* __restrict__ convb,
    const float* __restrict__ dtb, const float* __restrict__ A_log,
    float* __restrict__ ws, int dir0, int dslm)
{
    __shared__ float u_s[67 * 17];
    __shared__ float xh_c[4096];     // [d][t] swizzled; becomes wx after fold
    __shared__ float Bs[4096];       // [n][t] swizzled
    __shared__ float Cc[4096];       // [n][t] swizzled
    __shared__ float dts[16 * 65];
    __shared__ float wbuf[16 * 65];  // halo [3][192] during proj; wbuf after
    const int tid = threadIdx.x;
    const int ck = blockIdx.x;
    const int b = blockIdx.y;
    const int dir = dir0 + blockIdx.z;
    float* base = ws + (size_t)(dslm * blockIdx.z) * PD;
    float* Dst = base + OFF_DST;
    float* chA = base + OFF_CHA;
    float* tile = base + OFF_TILE + (size_t)(b * 128 + ck) * 6144;
    const int l0 = ck * 64;
    float* halo = wbuf;  // [3][192], live only during proj

    stage_u<512>(x, u_s, b, l0, dir, tid);
    __syncthreads();

    const int lane = tid & 63;
    const int wv = __builtin_amdgcn_readfirstlane(tid >> 6);

    f32x2 u2[8];
    {
        const float* ur = &u_s[(lane + 3) * 17];
        #pragma unroll
        for (int k = 0; k < 8; k++) { u2[k].x = ur[2 * k]; u2[k].y = ur[2 * k + 1]; }
    }
    // halo: pre-conv xBC at l0-3..l0-1 for ch 0..191
    if (tid < 192) {
        f32x2 uh2[8];
        #pragma unroll
        for (int pos = 0; pos < 3; pos++) {
            const float* uhr = &u_s[pos * 17];
            #pragma unroll
            for (int k = 0; k < 8; k++) { uh2[k].x = uhr[2 * k]; uh2[k].y = uhr[2 * k + 1]; }
            halo[pos * 192 + tid] = pk_dot16(uh2, Win + (size_t)(dir * 272 + 64 + tid) * 16);
        }
    }
    __syncthreads();

    // proj cols 64..271 (xh, B, C, dt); 8 waves x 26 cols
    for (int i = 0; i < 26; i++) {
        const int col = 64 + wv * 26 + i;
        float acc = pk_dot16(u2, Win + (size_t)(dir * 272 + col) * 16);
        if (col < 256) {
            const int ch = col - 64;
            float v1 = __shfl_up(acc, 1);
            float v2 = __shfl_up(acc, 2);
            float v3 = __shfl_up(acc, 3);
            float hh0 = halo[ch];
            float hh1 = halo[192 + ch];
            float hh2 = halo[384 + ch];
            float m1 = (lane >= 1) ? v1 : hh2;
            float m2 = (lane >= 2) ? v2 : ((lane == 0) ? hh1 : hh2);
            float m3 = (lane >= 3) ? v3 : ((lane == 0) ? hh0 : ((lane == 1) ? hh1 : hh2));
            const float* cwp = convw + (size_t)(dir * CONVD + ch) * 4;
            float conv = convb[dir * CONVD + ch]
                       + cwp[0] * m3 + cwp[1] * m2 + cwp[2] * m1 + cwp[3] * acc;
            float xv = fast_silu(conv);
            if (ch < 64)       xh_c[XSW(ch, lane)] = xv;
            else if (ch < 128) Bs[XSW(ch - 64, lane)] = xv;
            else               Cc[XSW(ch - 128, lane)] = xv;
        } else {
            const int h = col - 256;
            float dv = fast_softplus(acc + dtb[dir * 16 + h]);
            dts[h * 65 + lane] = dv;
            tile[TDT + h * 64 + lane] = dv;
        }
    }
    __syncthreads();

    // per-head scan (writes ct2 tile + wbuf; halo region dead)
    for (int h = wv; h < 16; h += 8) {
        float A2 = -expf(A_log[dir * 16 + h]) * LOG2E;
        float dtv = dts[h * 65 + lane];
        float v = dtv * A2;
        #pragma unroll
        for (int off = 1; off < 64; off <<= 1) {
            float o = __shfl_up(v, off, 64);
            if (lane >= off) v += o;
        }
        float tot = __shfl(v, 63, 64);
        tile[TCT + h * 64 + lane] = v;
        wbuf[h * 65 + lane] = __builtin_amdgcn_exp2f(tot - v) * dtv;
        if (lane == 63) chA[(b * 16 + h) * 128 + ck] = __builtin_amdgcn_exp2f(tot);
    }
    __syncthreads();

    // wx fold
    for (int j = tid; j < 4096; j += 512) {
        int hp = j >> 6, t = j & 63;
        xh_c[XSW(hp, t)] *= wbuf[(hp >> 2) * 65 + t];
    }
    __syncthreads();

    if (tid < 256) {
        // Dst delta: D[hp][n] = sum_t wx[hp][t] * B[n][t]
        const int hp4 = tid >> 4, n4 = tid & 15;
        f32x2 a2[4][4] = {};
        for (int tq = 0; tq < 16; tq++) {
            float4 xv[4], bv[4];
            #pragma unroll
            for (int i2 = 0; i2 < 4; i2++) {
                xv[i2] = *(const float4*)&xh_c[XSW4(4 * hp4 + i2, tq)];
                bv[i2] = *(const float4*)&Bs[XSW4(4 * n4 + i2, tq)];
            }
            #pragma unroll
            for (int i2 = 0; i2 < 4; i2++)
                #pragma unroll
                for (int j2 = 0; j2 < 4; j2++) {
                    a2[i2][j2] = pk_fma(lo2(xv[i2]), lo2(bv[j2]), a2[i2][j2]);
                    a2[i2][j2] = pk_fma(hi2(xv[i2]), hi2(bv[j2]), a2[i2][j2]);
                }
        }
        #pragma unroll
        for (int i2 = 0; i2 < 4; i2++) {
            int hp = 4 * hp4 + i2;
            int h = hp >> 2, p = hp & 3;
            *(float4*)(Dst + ((size_t)((b * 16 + h) * 128 + ck)) * 256 + p * 64 + 4 * n4) =
                make_float4(a2[i2][0].x + a2[i2][0].y, a2[i2][1].x + a2[i2][1].y,
                            a2[i2][2].x + a2[i2][2].y, a2[i2][3].x + a2[i2][3].y);
        }
    } else {
        // G[t][s] = sum_n C[n][t] * B[n][s]  (round-9-verified LDS reads)
        const int tg2 = tid - 256;
        const int t4g = tg2 >> 4, x4g = tg2 & 15;
        float G_[4][4] = {};
        for (int n = 0; n < 64; n++) {
            float4 cr4 = *(const float4*)&Cc[XSW4(n, t4g)];
            float4 br4 = *(const float4*)&Bs[XSW4(n, x4g)];
            float cr[4] = {cr4.x, cr4.y, cr4.z, cr4.w};
            float br_[4] = {br4.x, br4.y, br4.z, br4.w};
            #pragma unroll
            for (int r = 0; r < 4; r++)
                #pragma unroll
                for (int q = 0; q < 4; q++)
                    G_[r][q] += cr[r] * br_[q];
        }
        float* gdst = tile + TG + (size_t)tg2 * 16;
        #pragma unroll
        for (int r = 0; r < 4; r++)
            *(float4*)(gdst + 4 * r) = make_float4(G_[r][0], G_[r][1], G_[r][2], G_[r][3]);
    }
}

// ---------------------------------------------------------------------------
// K_SCAN: inter-chunk scan, in place.
// ---------------------------------------------------------------------------
__global__ __launch_bounds__(64) void k_chunk_scan(
    float* __restrict__ ws, int dslm)
{
    float* base = ws + (size_t)(dslm * blockIdx.z) * PD;
    float* Dst = base + OFF_DST;
    const float* chA = base + OFF_CHA;
    const int bh = blockIdx.x >> 2;
    const int elem = (blockIdx.x & 3) * 64 + threadIdx.x;
    float S = 0.f;
    for (int k0 = 0; k0 < NC; k0 += 8) {
        float d[8], av[8];
        #pragma unroll
        for (int j = 0; j < 8; j++) {
            d[j] = Dst[((size_t)(bh * 128 + k0 + j)) * 256 + elem];
            av[j] = chA[bh * 128 + k0 + j];
        }
        #pragma unroll
        for (int j = 0; j < 8; j++) {
            Dst[((size_t)(bh * 128 + k0 + j)) * 256 + elem] = S;
            S = av[j] * S + d[j];
        }
    }
}

// ---------------------------------------------------------------------------
// K_OUT_EPI: recomputes xh, C, z from x (round-9 proj path, no B/dt/scan);
// loads G/dt/ct2/Sin tiles; CS n-split + exchange; phase F/G round-8 forms.
// G loaded AFTER phase C to keep VGPR at round-9 levels.
// grid (128 ck, 8 b, nz), 512 threads.
// ---------------------------------------------------------------------------
__global__ __launch_bounds__(512, 2) void k_out_epi(
    const float* __restrict__ x, const float* __restrict__ Win,
    const float* __restrict__ convw, const float* __restrict__ convb,
    const float* __restrict__ Dp, const float* __restrict__ normw,
    const float* __restrict__ Wout, float* __restrict__ ws, int dir0, int dslm)
{
    __shared__ float SinT[64 * 68];   // [n][hp] stride 68; then grp0 CS-ex [256][17]
    __shared__ float xh_c[4096];      // [d][t] swizzled (recomputed)
    __shared__ float Bz[4096];        // z [d][t] swizzled (recomputed)
    __shared__ float Cy[4352];        // C [n][t] swizzled; grp1 CS-ex; then yv
    __shared__ float uW[67 * 17];     // u_s, then halo [3][192], then WoN [16][65]
    __shared__ float dts[16 * 68];
    __shared__ float ct2l[16 * 68];   // red[4][34] aliased here in phase G
    __shared__ float Dps[16];
    float* base = ws + (size_t)(dslm * blockIdx.z) * PD;
    const float* Dst = base + OFF_DST;
    float* ys        = base + OFF_YS;
    float* partials  = base + OFF_PART;
    const float* tile = base + OFF_TILE + (size_t)(blockIdx.y * 128 + blockIdx.x) * 6144;
    const int dir = dir0 + blockIdx.z;
    const int tid = threadIdx.x;
    const int b = blockIdx.y;
    const int ck = blockIdx.x;
    const int l0 = ck * 64;
    const int tg = tid & 255;
    const int t4 = tg >> 4, x4 = tg & 15;
    const int grp = tid >> 8;
    const int lane = tid & 63;
    const int wv = __builtin_amdgcn_readfirstlane(tid >> 6);

    // phase A: stage u; load Sin/dt/ct2 tiles; Dps
    stage_u<512>(x, uW, b, l0, dir, tid);
    if (tid < 256) {
        int h = tid >> 4, tq = tid & 15;
        *(float4*)&dts[h * 68 + 4 * tq]  = ((const float4*)(tile + TDT))[tid];
        *(float4*)&ct2l[h * 68 + 4 * tq] = ((const float4*)(tile + TCT))[tid];
    }
    for (int j = tid; j < 1024; j += 512) {
        int hp = j >> 4, n4 = (j & 15) << 2;
        int h = hp >> 2, p = hp & 3;
        float4 sv = *(const float4*)(Dst + ((size_t)((b * 16 + h) * 128 + ck)) * 256 + p * 64 + n4);
        SinT[(n4 + 0) * 68 + hp] = sv.x;
        SinT[(n4 + 1) * 68 + hp] = sv.y;
        SinT[(n4 + 2) * 68 + hp] = sv.z;
        SinT[(n4 + 3) * 68 + hp] = sv.w;
    }
    if (tid < 16) Dps[tid] = Dp[dir * 16 + tid];
    __syncthreads();

    // phase A2: u into regs, then halo into uW's low region
    f32x2 u2[8];
    {
        const float* ur = &uW[(lane + 3) * 17];
        #pragma unroll
        for (int k = 0; k < 8; k++) { u2[k].x = ur[2 * k]; u2[k].y = ur[2 * k + 1]; }
    }
    f32x2 uh2[8];
    if (tid < 192) {
        // each halo thread snapshots rows 0..2 (reads before overwrite)
        #pragma unroll
        for (int k = 0; k < 8; k++) { uh2[k].x = uW[2 * k]; uh2[k].y = uW[2 * k + 1]; }
        #pragma unroll
        for (int k = 0; k < 8; k++) {
            uh2[k].x = 0.f;  // placeholder, rewritten below per pos
        }
    }
    __syncthreads();
    float* halo = uW;  // [3][192] overlays u_s rows 0..33 (dead after u2 reads)
    if (tid < 192) {
        #pragma unroll
        for (int pos = 0; pos < 3; pos++) {
            // NOTE: must re-read u_s row BEFORE any halo write to this region.
            // Rows 0..2 occupy uW[0..51); halo writes start at uW[0]. To avoid
            // overwrite hazards we buffered nothing: instead read row pos fresh
            // here only if it hasn't been overwritten. Safe because halo writes
            // for pos p land at [p*192, p*192+192) which overlaps rows >= 0 of
            // u_s; so we must have snapshotted. We snapshot per-pos below.
            (void)0;
        }
    }
    // Simpler and safe: snapshot all three halo rows into regs first, then write.
    f32x2 uh0[8], uh1[8], uh2b[8];
    if (tid < 192) {
        #pragma unroll
        for (int k = 0; k < 8; k++) {
            uh0[k].x = uW[0 * 17 + 2 * k];  uh0[k].y = uW[0 * 17 + 2 * k + 1];
            uh1[k].x = uW[1 * 17 + 2 * k];  uh1[k].y = uW[1 * 17 + 2 * k + 1];
            uh2b[k].x = uW[2 * 17 + 2 * k]; uh2b[k].y = uW[2 * 17 + 2 * k + 1];
        }
    }
    __syncthreads();
    if (tid < 192) {
        const float* wp = Win + (size_t)(dir * 272 + 64 + tid) * 16;
        halo[0 * 192 + tid] = pk_dot16(uh0, wp);
        halo[1 * 192 + tid] = pk_dot16(uh1, wp);
        halo[2 * 192 + tid] = pk_dot16(uh2b, wp);
    }
    __syncthreads();

    // phase B: proj 192 cols (z 0..63, xh 64..127, C 192..255); 8 waves x 24
    for (int i = 0; i < 24; i++) {
        const int j = wv * 24 + i;
        const int pcol = (j < 128) ? j : (j + 64);
        float acc = pk_dot16(u2, Win + (size_t)(dir * 272 + pcol) * 16);
        if (pcol < 64) {
            Bz[XSW(pcol, lane)] = acc;
        } else {
            const int ch = pcol - 64;
            float v1 = __shfl_up(acc, 1);
            float v2 = __shfl_up(acc, 2);
            float v3 = __shfl_up(acc, 3);
            float hh0 = halo[ch];
            float hh1 = halo[192 + ch];
            float hh2 = halo[384 + ch];
            float m1 = (lane >= 1) ? v1 : hh2;
            float m2 = (lane >= 2) ? v2 : ((lane == 0) ? hh1 : hh2);
            float m3 = (lane >= 3) ? v3 : ((lane == 0) ? hh0 : ((lane == 1) ? hh1 : hh2));
            const float* cwp = convw + (size_t)(dir * CONVD + ch) * 4;
            float conv = convb[dir * CONVD + ch]
                       + cwp[0] * m3 + cwp[1] * m2 + cwp[2] * m1 + cwp[3] * acc;
            float xv = fast_silu(conv);
            if (ch < 64) xh_c[XSW(ch, lane)] = xv;
            else         Cy[XSW(ch - 128, lane)] = xv;
        }
    }
    __syncthreads();

    // phase C: CS over this group's n-half (round-9 swizzled C reads)
    float CS_[4][4] = {};
    {
        const int n0 = grp << 5;
        for (int n = n0; n < n0 + 32; n++) {
            float4 cr4 = *(const float4*)&Cy[XSW4(n, t4)];
            float cr[4] = {cr4.x, cr4.y, cr4.z, cr4.w};
            float sn[4];
            #pragma unroll
            for (int q = 0; q < 4; q++) sn[q] = SinT[n * 68 + 4 * x4 + q];
            #pragma unroll
            for (int r = 0; r < 4; r++)
                #pragma unroll
                for (int q = 0; q < 4; q++)
                    CS_[r][q] += cr[r] * sn[q];
        }
    }
    __syncthreads();  // C, Sin reads done

    // exchange partials; WoN stage (overwrites u_s/halo region of uW)
    {
        float* ex = (grp == 0) ? SinT : Cy;
        #pragma unroll
        for (int k = 0; k < 16; k++) ex[tg * 17 + k] = CS_[k >> 2][k & 3];
    }
    for (int j = tid; j < 1024; j += 512) {
        int c = j >> 6, d = j & 63;
        uW[c * 65 + d] = Wout[dir * 1024 + j] * normw[dir * 64 + d];
    }
    __syncthreads();
    {
        const float* ex = (grp == 0) ? Cy : SinT;
        #pragma unroll
        for (int k = 0; k < 16; k++) CS_[k >> 2][k & 3] += ex[tg * 17 + k];
    }
    // load G now (deferred to minimize live range)
    float G_[4][4];
    {
        const float* gsrc = tile + TG + (size_t)tg * 16;
        #pragma unroll
        for (int r = 0; r < 4; r++) {
            float4 g4 = *(const float4*)(gsrc + 4 * r);
            G_[r][0] = g4.x; G_[r][1] = g4.y; G_[r][2] = g4.z; G_[r][3] = g4.w;
        }
    }
    __syncthreads();  // exchange reads done; Cy becomes yv

    // phase F: group g handles heads 8g..8g+7; results -> yv (round-8 form)
    float* yv = Cy;  // [64 rows][4 p][17]
    const int tbase = 4 * t4;
    #pragma unroll 1
    for (int hh = 0; hh < 8; hh++) {
        const int h = 8 * grp + hh;
        const float* ctp = &ct2l[h * 68];
        const float* dtp = &dts[h * 68];
        float4 ctt4 = *(const float4*)&ctp[tbase];
        const float ctt[4] = {ctt4.x, ctt4.y, ctt4.z, ctt4.w};
        float ect[4];
        #pragma unroll
        for (int r = 0; r < 4; r++) ect[r] = __builtin_amdgcn_exp2f(ctt[r]);
        float4 cs4 = *(const float4*)&ctp[4 * x4];
        float4 dt4 = *(const float4*)&dtp[4 * x4];
        float v[16] = {0.f, 0.f, 0.f, 0.f, 0.f, 0.f, 0.f, 0.f,
                       0.f, 0.f, 0.f, 0.f, 0.f, 0.f, 0.f, 0.f};
        #pragma unroll
        for (int q = 0; q < 4; q++) {
            const int s = 4 * x4 + q;
            float csq = (q == 0) ? cs4.x : (q == 1) ? cs4.y : (q == 2) ? cs4.z : cs4.w;
            float dtq = (q == 0) ? dt4.x : (q == 1) ? dt4.y : (q == 2) ? dt4.z : dt4.w;
            float xv[4];
            #pragma unroll
            for (int p = 0; p < 4; p++) {
                int m = 4 * h + p;
                xv[p] = xh_c[m * 64 + (((x4 ^ (m & 15)) & 15) << 2) + q];
            }
            #pragma unroll
            for (int r = 0; r < 4; r++) {
                float e = __builtin_amdgcn_exp2f(ctt[r] - csq);
                float w = (s <= tbase + r) ? (G_[r][q] * dtq) * e : 0.f;
                #pragma unroll
                for (int p = 0; p < 4; p++) v[4 * r + p] += w * xv[p];
            }
        }
        if (x4 == h) {
            #pragma unroll
            for (int r = 0; r < 4; r++)
                #pragma unroll
                for (int p = 0; p < 4; p++)
                    v[4 * r + p] += ect[r] * CS_[r][p];
        }
        // butterfly reduce-scatter over 16 lanes: lane x4 ends with S[x4]
        #pragma unroll
        for (int j = 0; j < 8; j++) {
            float a = (x4 & 8) ? v[j + 8] : v[j];
            float s_ = (x4 & 8) ? v[j] : v[j + 8];
            v[j] = a + __shfl_xor(s_, 8);
        }
        #pragma unroll
        for (int j = 0; j < 4; j++) {
            float a = (x4 & 4) ? v[j + 4] : v[j];
            float s_ = (x4 & 4) ? v[j] : v[j + 4];
            v[j] = a + __shfl_xor(s_, 4);
        }
        #pragma unroll
        for (int j = 0; j < 2; j++) {
            float a = (x4 & 2) ? v[j + 2] : v[j];
            float s_ = (x4 & 2) ? v[j] : v[j + 2];
            v[j] = a + __shfl_xor(s_, 2);
        }
        {
            float a = (x4 & 1) ? v[1] : v[0];
            float s_ = (x4 & 1) ? v[0] : v[1];
            v[0] = a + __shfl_xor(s_, 1);
        }
        const int row = tbase + (x4 >> 2);
        yv[(row * 4 + (x4 & 3)) * 17 + h] = v[0];
    }
    __syncthreads();

    // phase G: epilogue on tid<256 (round-8 form); red aliased onto ct2l
    float* red = ct2l;  // [4][34], ct2l dead after phase F
    float os[4];
    const int row = tid >> 2;
    const int p = tid & 3;
    if (tid < 256) {
        float gg[16], sumsq = 0.f;
        #pragma unroll
        for (int h = 0; h < 16; h++) {
            float yval = yv[(row * 4 + p) * 17 + h];
            int m = 4 * h + p;
            int ax = m * 64 + ((((row >> 2) ^ (m & 15)) & 15) << 2) + (row & 3);
            float xh = xh_c[ax];
            float zv = Bz[ax];
            float val = (yval + Dps[h] * xh) * fast_silu(zv);
            gg[h] = val;
            sumsq += val * val;
        }
        sumsq += __shfl_xor(sumsq, 1);
        sumsq += __shfl_xor(sumsq, 2);
        float rms = rsqrtf(sumsq * (1.f / 64.f) + 1e-5f);

        float oc[16];
        #pragma unroll
        for (int c = 0; c < 16; c++) {
            float a = 0.f;
            #pragma unroll
            for (int h = 0; h < 16; h++) a += gg[h] * uW[c * 65 + 4 * h + p];
            oc[c] = a;
        }
        #pragma unroll
        for (int c = 0; c < 16; c++) {
            oc[c] += __shfl_xor(oc[c], 1);
            oc[c] += __shfl_xor(oc[c], 2);
        }
        #pragma unroll
        for (int i2 = 0; i2 < 4; i2++) {
            float a0 = (p == 0) ? oc[i2] : oc[4 + i2];
            float a1 = (p == 2) ? oc[8 + i2] : oc[12 + i2];
            os[i2] = (((p & 2) == 0) ? a0 : a1) * rms;
        }
        size_t bl = (size_t)(b * 8192 + l0 + row);
        *(float4*)(ys + bl * 16 + 4 * p) = make_float4(os[0], os[1], os[2], os[3]);

        // BN partials
        float bs[4], bq[4];
        #pragma unroll
        for (int i2 = 0; i2 < 4; i2++) {
            float vv = fmaxf(os[i2], 0.f);
            bs[i2] = vv;
            bq[i2] = vv * vv;
        }
        #pragma unroll
        for (int off = 4; off < 64; off <<= 1) {
            #pragma unroll
            for (int i2 = 0; i2 < 4; i2++) {
                bs[i2] += __shfl_xor(bs[i2], off);
                bq[i2] += __shfl_xor(bq[i2], off);
            }
        }
        const int wlane = tid & 63, wvid = tid >> 6;
        if (wlane < 4) {
            #pragma unroll
            for (int i2 = 0; i2 < 4; i2++) {
                red[wvid * 34 + 4 * wlane + i2] = bs[i2];
                red[wvid * 34 + 16 + 4 * wlane + i2] = bq[i2];
            }
        }
    }
    __syncthreads();
    if (tid < 32) {
        float a = red[0 * 34 + tid] + red[1 * 34 + tid]
                + red[2 * 34 + tid] + red[3 * 34 + tid];
        partials[((size_t)(b * 128 + ck)) * 32 + tid] = a;
    }
}

// ---------------------------------------------------------------------------
// K_POOL_BN: reduce partials -> BN coefs, then BN + linear + maxpool(32).
// ---------------------------------------------------------------------------
__global__ __launch_bounds__(256) void k_pool_bn(
    const float* __restrict__ gamma, const float* __restrict__ beta,
    const float* __restrict__ lin_w, const float* __restrict__ lin_b,
    float* __restrict__ ws, float* __restrict__ out, int dir0, int dslm)
{
    float* base = ws + (size_t)(dslm * blockIdx.z) * PD;
    const float* ys = base + OFF_YS;
    const float* partials = base + OFF_PART;
    const int dir = dir0 + blockIdx.z;
    const int tid = threadIdx.x;
    __shared__ float red[8][33];
    __shared__ float cf[18];
    {
        int c = tid & 31, ks = tid >> 5;
        float a = 0.f;
        for (int k = ks * 128; k < ks * 128 + 128; k++) a += partials[k * 32 + c];
        red[ks][c] = a;
    }
    __syncthreads();
    if (tid < 32) {
        float a = 0.f;
        #pragma unroll
        for (int s2 = 1; s2 < 8; s2++) a += red[s2][tid];
        red[0][tid] += a;
    }
    __syncthreads();
    if (tid == 0) {
        float off = lin_b[dir];
        for (int c = 0; c < 16; c++) {
            float mu = red[0][c] * (1.f / 65536.f);
            float var = red[0][16 + c] * (1.f / 65536.f) - mu * mu;
            float inv = rsqrtf(var + 1e-5f);
            float coef = inv * gamma[dir * 16 + c] * lin_w[dir * 16 + c];
            cf[c] = coef;
            off += beta[dir * 16 + c] * lin_w[dir * 16 + c] - mu * coef;
        }
        cf[16] = off;
    }
    __syncthreads();

    const int b = blockIdx.x >> 3;
    const int jg = blockIdx.x & 7;
    const int j = jg * 32 + (tid >> 3);
    const int sub = tid & 7;
    float m = -3.4e38f;
    #pragma unroll
    for (int r = 0; r < 4; r++) {
        int l = j * PW + 8 * r + sub;
        const float* rowp = ys + (size_t)(b * 8192 + l) * 16;
        float sv = cf[16];
        #pragma unroll
        for (int k = 0; k < 4; k++) {
            float4 v4 = *(const float4*)(rowp + 4 * k);
            sv += fmaxf(v4.x, 0.f) * cf[4 * k] + fmaxf(v4.y, 0.f) * cf[4 * k + 1]
                + fmaxf(v4.z, 0.f) * cf[4 * k + 2] + fmaxf(v4.w, 0.f) * cf[4 * k + 3];
        }
        m = fmaxf(m, sv);
    }
    m = fmaxf(m, __shfl_xor(m, 1));
    m = fmaxf(m, __shfl_xor(m, 2));
    m = fmaxf(m, __shfl_xor(m, 4));
    if (sub == 0) out[b * 768 + dir * 256 + j] = m;
}

// ---------------------------------------------------------------------------
extern "C" void kernel_launch(void* const* d_in, const int* in_sizes, int n_in,
                              void* d_out, int out_size, void* d_ws, size_t ws_size,
                              hipStream_t stream) {
    const float* x     = (const float*)d_in[0];
    const float* Win   = (const float*)d_in[1];
    const float* convw = (const float*)d_in[2];
    const float* convb = (const float*)d_in[3];
    const float* dtb   = (const float*)d_in[4];
    const float* Alog  = (const float*)d_in[5];
    const float* Dp    = (const float*)d_in[6];
    const float* normw = (const float*)d_in[7];
    const float* Wout  = (const float*)d_in[8];
    const float* gamma = (const float*)d_in[9];
    const float* beta  = (const float*)d_in[10];
    const float* linw  = (const float*)d_in[11];
    const float* linb  = (const float*)d_in[12];
    float* out = (float*)d_out;
    float* ws = (float*)d_ws;

    const bool batched = ws_size >= (size_t)3 * PD * 4;
    const int nz = batched ? 3 : 1;
    const int dslm = batched ? 1 : 0;
    const int nloop = batched ? 1 : 3;

    for (int d0 = 0; d0 < nloop; ++d0) {
        k_front<<<dim3(128, 8, nz), dim3(512), 0, stream>>>(
            x, Win, convw, convb, dtb, Alog, ws, d0, dslm);
        k_chunk_scan<<<dim3(512, 1, nz), dim3(64), 0, stream>>>(ws, dslm);
        k_out_epi<<<dim3(128, 8, nz), dim3(512), 0, stream>>>(
            x, Win, convw, convb, Dp, normw, Wout, ws, d0, dslm);
        k_pool_bn<<<dim3(64, 1, nz), dim3(256), 0, stream>>>(
            gamma, beta, linw, linb, ws, out, d0, dslm);
    }
}

// Round 14
// 356.371 us; speedup vs baseline: 1.3522x; 1.3522x over previous
//
#include <hip/hip_runtime.h>
#include <math.h>

#define CONVD 192
#define NC 128
#define PW 32
#define LOG2E 1.4426950408889634f
#define LN2f  0.69314718055994531f

// per-dir workspace offsets (floats)
#define OFF_DST   0u          // Dst  [8*16][128][256]  (delta -> Sin after scan)
#define OFF_CHA   4194304u    // chA  [8*16][128]
#define OFF_YS    4210688u    // ys   [8][8192][16]
#define OFF_PART  5259264u    // partials [1024][32]
#define PD        5292032u    // floats per dir region (21.2 MB)

// XOR-quad swizzle for [64][64] LDS tiles, element (row m, col t)
#define XSW(m, t)   ((m) * 64 + (((((t) >> 2) ^ ((m) & 15)) & 15) << 2) + ((t) & 3))
#define XSW4(m, tq) ((m) * 64 + ((((tq) ^ ((m) & 15)) & 15) << 2))

typedef float f32x2 __attribute__((ext_vector_type(2)));

// packed fp32 FMA (VOP3P, 2x fp32 rate). op_sel variants broadcast one half
// of a source to both lanes at zero cost.
__device__ __forceinline__ f32x2 pk_fma(f32x2 a, f32x2 b, f32x2 c) {
    f32x2 d;
    asm("v_pk_fma_f32 %0, %1, %2, %3" : "=v"(d) : "v"(a), "v"(b), "v"(c));
    return d;
}
__device__ __forceinline__ f32x2 pk_fma_alo(f32x2 a, f32x2 b, f32x2 c) {
    f32x2 d;  // both lanes use a.lo
    asm("v_pk_fma_f32 %0, %1, %2, %3 op_sel_hi:[0,1,1]" : "=v"(d) : "v"(a), "v"(b), "v"(c));
    return d;
}
__device__ __forceinline__ f32x2 pk_fma_ahi(f32x2 a, f32x2 b, f32x2 c) {
    f32x2 d;  // both lanes use a.hi
    asm("v_pk_fma_f32 %0, %1, %2, %3 op_sel:[1,0,0]" : "=v"(d) : "v"(a), "v"(b), "v"(c));
    return d;
}
__device__ __forceinline__ f32x2 pk_fma_blo(f32x2 a, f32x2 b, f32x2 c) {
    f32x2 d;  // both lanes use b.lo
    asm("v_pk_fma_f32 %0, %1, %2, %3 op_sel_hi:[1,0,1]" : "=v"(d) : "v"(a), "v"(b), "v"(c));
    return d;
}
__device__ __forceinline__ f32x2 pk_fma_bhi(f32x2 a, f32x2 b, f32x2 c) {
    f32x2 d;  // both lanes use b.hi
    asm("v_pk_fma_f32 %0, %1, %2, %3 op_sel:[0,1,0]" : "=v"(d) : "v"(a), "v"(b), "v"(c));
    return d;
}
__device__ __forceinline__ f32x2 lo2(float4 v) { f32x2 r; r.x = v.x; r.y = v.y; return r; }
__device__ __forceinline__ f32x2 hi2(float4 v) { f32x2 r; r.x = v.z; r.y = v.w; return r; }

__device__ __forceinline__ float fast_silu(float x) {
    float e = __builtin_amdgcn_exp2f(-x * LOG2E);
    return x * __builtin_amdgcn_rcpf(1.f + e);
}
__device__ __forceinline__ float fast_softplus(float x) {
    if (x > 20.f) return x;
    float e = __builtin_amdgcn_exp2f(x * LOG2E);
    return LN2f * __builtin_amdgcn_logf(1.f + e);
}

// stage u rows [pos][c] (67 x 16, pad 17) with 3-halo, zeros for l<0
template<int NT>
__device__ __forceinline__ void stage_u(
    const float* __restrict__ x, float* u_s, int b, int l0, int dir, int tid)
{
    for (int i = tid; i < 67 * 16; i += NT) {
        int pos = i >> 4, c = i & 15;
        int l = l0 + pos - 3;
        float v = 0.f;
        if (l >= 0) {
            if (dir == 0) {
                v = x[(b * 16 + c) * 8192 + l];
            } else if (dir == 1) {
                int h = l >> 9, w = (l >> 5) & 15, d = l & 31;
                v = x[(((b * 16 + c) * 32 + d) * 16 + h) * 16 + w];
            } else {
                int w = l >> 9, d = (l >> 4) & 31, h = l & 15;
                v = x[(((b * 16 + c) * 32 + d) * 16 + h) * 16 + w];
            }
        }
        u_s[pos * 17 + c] = v;
    }
}

// packed dot(u2[8], 16-float weight row)
__device__ __forceinline__ float pk_dot16(const f32x2* u2, const float* wp) {
    float4 w0 = *(const float4*)(wp);
    float4 w1 = *(const float4*)(wp + 4);
    float4 w2 = *(const float4*)(wp + 8);
    float4 w3 = *(const float4*)(wp + 12);
    f32x2 a = {0.f, 0.f};
    a = pk_fma(u2[0], lo2(w0), a);
    a = pk_fma(u2[1], hi2(w0), a);
    a = pk_fma(u2[2], lo2(w1), a);
    a = pk_fma(u2[3], hi2(w1), a);
    a = pk_fma(u2[4], lo2(w2), a);
    a = pk_fma(u2[5], hi2(w2), a);
    a = pk_fma(u2[6], lo2(w3), a);
    a = pk_fma(u2[7], hi2(w3), a);
    return a.x + a.y;
}

// ---------------------------------------------------------------------------
// K_DELTA: proj (xh, B, dt only) + conv + silu + scan + chunk state delta.
// (round-9 verified version)
// ---------------------------------------------------------------------------
__global__ __launch_bounds__(512, 6) void k_delta(
    const float* __restrict__ x, const float* __restrict__ Win,
    const float* __restrict__ convw, const float* __restrict__ convb,
    const float* __restrict__ dtb, const float* __restrict__ A_log,
    float* __restrict__ ws, int dir0, int dslm)
{
    __shared__ float u_s[67 * 17];
    __shared__ float xh_c[4096];
    __shared__ float Bs[4096];
    __shared__ float dts[16 * 65];
    __shared__ float wbuf[16 * 65];  // halo[3][128] before scan phase
    const int tid = threadIdx.x;
    const int ck = blockIdx.x;
    const int b = blockIdx.y;
    const int dir = dir0 + blockIdx.z;
    float* base = ws + (size_t)(dslm * blockIdx.z) * PD;
    float* Dst = base + OFF_DST;
    float* chA = base + OFF_CHA;
    const int l0 = ck * 64;
    float* halo = wbuf;  // [3][128], live only during proj phase

    stage_u<512>(x, u_s, b, l0, dir, tid);
    __syncthreads();

    const int lane = tid & 63;
    const int wv = __builtin_amdgcn_readfirstlane(tid >> 6);

    f32x2 u2[8];
    {
        const float* ur = &u_s[(lane + 3) * 17];
        #pragma unroll
        for (int k = 0; k < 8; k++) { u2[k].x = ur[2 * k]; u2[k].y = ur[2 * k + 1]; }
    }
    // halo: pre-conv xBC at l0-3..l0-1 for ch 0..127
    if (tid < 128) {
        f32x2 uh2[8];
        #pragma unroll
        for (int pos = 0; pos < 3; pos++) {
            const float* uhr = &u_s[pos * 17];
            #pragma unroll
            for (int k = 0; k < 8; k++) { uh2[k].x = uhr[2 * k]; uh2[k].y = uhr[2 * k + 1]; }
            halo[pos * 128 + tid] = pk_dot16(uh2, Win + (size_t)(dir * 272 + 64 + tid) * 16);
        }
    }
    __syncthreads();

    for (int i = 0; i < 18; i++) {
        const int g = wv * 18 + i;
        const int col = (g < 128) ? (64 + g) : (256 + (g - 128));
        float acc = pk_dot16(u2, Win + (size_t)(dir * 272 + col) * 16);
        if (col < 256) {
            const int ch = col - 64;
            float v1 = __shfl_up(acc, 1);
            float v2 = __shfl_up(acc, 2);
            float v3 = __shfl_up(acc, 3);
            float hh0 = halo[ch];
            float hh1 = halo[128 + ch];
            float hh2 = halo[256 + ch];
            float m1 = (lane >= 1) ? v1 : hh2;
            float m2 = (lane >= 2) ? v2 : ((lane == 0) ? hh1 : hh2);
            float m3 = (lane >= 3) ? v3 : ((lane == 0) ? hh0 : ((lane == 1) ? hh1 : hh2));
            const float* cwp = convw + (size_t)(dir * CONVD + ch) * 4;
            float conv = convb[dir * CONVD + ch]
                       + cwp[0] * m3 + cwp[1] * m2 + cwp[2] * m1 + cwp[3] * acc;
            float xv = fast_silu(conv);
            if (ch < 64) xh_c[XSW(ch, lane)] = xv;
            else         Bs[XSW(ch - 64, lane)] = xv;
        } else {
            const int h = col - 256;
            dts[h * 65 + lane] = fast_softplus(acc + dtb[dir * 16 + h]);
        }
    }
    __syncthreads();

    for (int h = wv; h < 16; h += 8) {
        float A2 = -expf(A_log[dir * 16 + h]) * LOG2E;
        float dtv = dts[h * 65 + lane];
        float v = dtv * A2;
        #pragma unroll
        for (int off = 1; off < 64; off <<= 1) {
            float o = __shfl_up(v, off, 64);
            if (lane >= off) v += o;
        }
        float tot = __shfl(v, 63, 64);
        wbuf[h * 65 + lane] = __builtin_amdgcn_exp2f(tot - v) * dtv;
        if (lane == 63) chA[(b * 16 + h) * 128 + ck] = __builtin_amdgcn_exp2f(tot);
    }
    __syncthreads();

    for (int j = tid; j < 4096; j += 512) {
        int hp = j >> 6, t = j & 63;
        xh_c[XSW(hp, t)] *= wbuf[(hp >> 2) * 65 + t];
    }
    __syncthreads();

    if (tid < 256) {
        const int hp4 = tid >> 4, n4 = tid & 15;
        f32x2 a2[4][4] = {};
        for (int tq = 0; tq < 16; tq++) {
            float4 xv[4], bv[4];
            #pragma unroll
            for (int i2 = 0; i2 < 4; i2++) {
                xv[i2] = *(const float4*)&xh_c[XSW4(4 * hp4 + i2, tq)];
                bv[i2] = *(const float4*)&Bs[XSW4(4 * n4 + i2, tq)];
            }
            #pragma unroll
            for (int i2 = 0; i2 < 4; i2++)
                #pragma unroll
                for (int j2 = 0; j2 < 4; j2++) {
                    a2[i2][j2] = pk_fma(lo2(xv[i2]), lo2(bv[j2]), a2[i2][j2]);
                    a2[i2][j2] = pk_fma(hi2(xv[i2]), hi2(bv[j2]), a2[i2][j2]);
                }
        }
        #pragma unroll
        for (int i2 = 0; i2 < 4; i2++) {
            int hp = 4 * hp4 + i2;
            int h = hp >> 2, p = hp & 3;
            *(float4*)(Dst + ((size_t)((b * 16 + h) * 128 + ck)) * 256 + p * 64 + 4 * n4) =
                make_float4(a2[i2][0].x + a2[i2][0].y, a2[i2][1].x + a2[i2][1].y,
                            a2[i2][2].x + a2[i2][2].y, a2[i2][3].x + a2[i2][3].y);
        }
    }
}

// ---------------------------------------------------------------------------
// K_SCAN: inter-chunk scan, in place.
// ---------------------------------------------------------------------------
__global__ __launch_bounds__(64) void k_chunk_scan(
    float* __restrict__ ws, int dslm)
{
    float* base = ws + (size_t)(dslm * blockIdx.z) * PD;
    float* Dst = base + OFF_DST;
    const float* chA = base + OFF_CHA;
    const int bh = blockIdx.x >> 2;
    const int elem = (blockIdx.x & 3) * 64 + threadIdx.x;
    float S = 0.f;
    for (int k0 = 0; k0 < NC; k0 += 8) {
        float d[8], av[8];
        #pragma unroll
        for (int j = 0; j < 8; j++) {
            d[j] = Dst[((size_t)(bh * 128 + k0 + j)) * 256 + elem];
            av[j] = chA[bh * 128 + k0 + j];
        }
        #pragma unroll
        for (int j = 0; j < 8; j++) {
            Dst[((size_t)(bh * 128 + k0 + j)) * 256 + elem] = S;
            S = av[j] * S + d[j];
        }
    }
}

// ---------------------------------------------------------------------------
// K_OUT_EPI: round-9 structure (halo precompute, pk proj, packed D/F split,
// G/CS exchange) with round-8's conflict-free WoN [16][65] + scalar epilogue.
// grid (128 ck, 8 b, nz), 512 threads.
// ---------------------------------------------------------------------------
__global__ __launch_bounds__(512, 4) void k_out_epi(
    const float* __restrict__ x, const float* __restrict__ Win,
    const float* __restrict__ convw, const float* __restrict__ convb,
    const float* __restrict__ dtb, const float* __restrict__ A_log,
    const float* __restrict__ Dp, const float* __restrict__ normw,
    const float* __restrict__ Wout, float* __restrict__ ws, int dir0, int dslm)
{
    __shared__ float SinT[64 * 66];   // [n][hp] stride 66; then CS exchange [16][129]
    __shared__ float xh_c[4096];      // [d][t] swizzled
    __shared__ float Bz[4096];        // B [n][t] swz, then z [d][t] swz
    __shared__ float Cy[4352];        // C [n][t] swz; then G exch [16][257]; then yv
    __shared__ float uW[67 * 17];     // u_s, then WoN [16][65]
    __shared__ float dts[16 * 68];
    __shared__ float ct2l[16 * 68];   // halo[3][192] before scan phase
    __shared__ float Dps[16];
    __shared__ float red[4][34];
    float* base = ws + (size_t)(dslm * blockIdx.z) * PD;
    const float* Dst = base + OFF_DST;
    float* ys        = base + OFF_YS;
    float* partials  = base + OFF_PART;
    const int dir = dir0 + blockIdx.z;
    const int tid = threadIdx.x;
    const int b = blockIdx.y;
    const int ck = blockIdx.x;
    const int l0 = ck * 64;
    const int tg = tid & 255;
    const int t4 = tg >> 4, x4 = tg & 15;
    const int grp = tid >> 8;
    const int lane = tid & 63;
    const int wv = __builtin_amdgcn_readfirstlane(tid >> 6);
    float* halo = ct2l;  // [3][192], live only during proj phase

    // phase A: stage u + SinT + Dps
    stage_u<512>(x, uW, b, l0, dir, tid);
    for (int j = tid; j < 1024; j += 512) {
        int hp = j >> 4, n4 = (j & 15) << 2;
        int h = hp >> 2, p = hp & 3;
        float4 sv = *(const float4*)(Dst + ((size_t)((b * 16 + h) * 128 + ck)) * 256 + p * 64 + n4);
        SinT[(n4 + 0) * 66 + hp] = sv.x;
        SinT[(n4 + 1) * 66 + hp] = sv.y;
        SinT[(n4 + 2) * 66 + hp] = sv.z;
        SinT[(n4 + 3) * 66 + hp] = sv.w;
    }
    if (tid < 16) Dps[tid] = Dp[dir * 16 + tid];
    __syncthreads();

    f32x2 u2[8];
    {
        const float* ur = &uW[(lane + 3) * 17];
        #pragma unroll
        for (int k = 0; k < 8; k++) { u2[k].x = ur[2 * k]; u2[k].y = ur[2 * k + 1]; }
    }
    // halo: pre-conv xBC at l0-3..l0-1 for ch 0..191
    if (tid < 192) {
        f32x2 uh2[8];
        #pragma unroll
        for (int pos = 0; pos < 3; pos++) {
            const float* uhr = &uW[pos * 17];
            #pragma unroll
            for (int k = 0; k < 8; k++) { uh2[k].x = uhr[2 * k]; uh2[k].y = uhr[2 * k + 1]; }
            halo[pos * 192 + tid] = pk_dot16(uh2, Win + (size_t)(dir * 272 + 64 + tid) * 16);
        }
    }
    __syncthreads();

    // phase B: proj cols 64..271 (xh, B, C, dt); 8 waves x 26 cols
    for (int i = 0; i < 26; i++) {
        const int col = 64 + wv * 26 + i;
        float acc = pk_dot16(u2, Win + (size_t)(dir * 272 + col) * 16);
        if (col < 256) {
            const int ch = col - 64;
            float v1 = __shfl_up(acc, 1);
            float v2 = __shfl_up(acc, 2);
            float v3 = __shfl_up(acc, 3);
            float hh0 = halo[ch];
            float hh1 = halo[192 + ch];
            float hh2 = halo[384 + ch];
            float m1 = (lane >= 1) ? v1 : hh2;
            float m2 = (lane >= 2) ? v2 : ((lane == 0) ? hh1 : hh2);
            float m3 = (lane >= 3) ? v3 : ((lane == 0) ? hh0 : ((lane == 1) ? hh1 : hh2));
            const float* cwp = convw + (size_t)(dir * CONVD + ch) * 4;
            float conv = convb[dir * CONVD + ch]
                       + cwp[0] * m3 + cwp[1] * m2 + cwp[2] * m1 + cwp[3] * acc;
            float xv = fast_silu(conv);
            if (ch < 64)       xh_c[XSW(ch, lane)] = xv;
            else if (ch < 128) Bz[XSW(ch - 64, lane)] = xv;
            else               Cy[XSW(ch - 128, lane)] = xv;
        } else {
            const int h = col - 256;
            dts[h * 68 + lane] = fast_softplus(acc + dtb[dir * 16 + h]);
        }
    }
    __syncthreads();

    // phase C: scan -> ct2 (LDS only, overwrites halo); 8 waves x 2 heads
    for (int h = wv; h < 16; h += 8) {
        float A2 = -expf(A_log[dir * 16 + h]) * LOG2E;
        float dtv = dts[h * 68 + lane];
        float v = dtv * A2;
        #pragma unroll
        for (int off = 1; off < 64; off <<= 1) {
            float o = __shfl_up(v, off, 64);
            if (lane >= off) v += o;
        }
        ct2l[h * 68 + lane] = v;
    }
    __syncthreads();

    // phase D split: group 0 -> G (full n); group 1 -> CS (full n). Packed.
    float G_[4][4], CS_[4][4];
    if (grp == 0) {
        f32x2 G2[4][2] = {};
        for (int n = 0; n < 64; n++) {
            float4 cr4 = *(const float4*)&Cy[XSW4(n, t4)];
            float4 br4 = *(const float4*)&Bz[XSW4(n, x4)];
            f32x2 c01 = lo2(cr4), c23 = hi2(cr4);
            f32x2 b01 = lo2(br4), b23 = hi2(br4);
            G2[0][0] = pk_fma_alo(c01, b01, G2[0][0]); G2[0][1] = pk_fma_alo(c01, b23, G2[0][1]);
            G2[1][0] = pk_fma_ahi(c01, b01, G2[1][0]); G2[1][1] = pk_fma_ahi(c01, b23, G2[1][1]);
            G2[2][0] = pk_fma_alo(c23, b01, G2[2][0]); G2[2][1] = pk_fma_alo(c23, b23, G2[2][1]);
            G2[3][0] = pk_fma_ahi(c23, b01, G2[3][0]); G2[3][1] = pk_fma_ahi(c23, b23, G2[3][1]);
        }
        #pragma unroll
        for (int r = 0; r < 4; r++) {
            G_[r][0] = G2[r][0].x; G_[r][1] = G2[r][0].y;
            G_[r][2] = G2[r][1].x; G_[r][3] = G2[r][1].y;
        }
    } else {
        f32x2 C2[4][2] = {};
        for (int n = 0; n < 64; n++) {
            float4 cr4 = *(const float4*)&Cy[XSW4(n, t4)];
            f32x2 c01 = lo2(cr4), c23 = hi2(cr4);
            f32x2 s01 = *(const f32x2*)&SinT[n * 66 + 4 * x4];
            f32x2 s23 = *(const f32x2*)&SinT[n * 66 + 4 * x4 + 2];
            C2[0][0] = pk_fma_alo(c01, s01, C2[0][0]); C2[0][1] = pk_fma_alo(c01, s23, C2[0][1]);
            C2[1][0] = pk_fma_ahi(c01, s01, C2[1][0]); C2[1][1] = pk_fma_ahi(c01, s23, C2[1][1]);
            C2[2][0] = pk_fma_alo(c23, s01, C2[2][0]); C2[2][1] = pk_fma_alo(c23, s23, C2[2][1]);
            C2[3][0] = pk_fma_ahi(c23, s01, C2[3][0]); C2[3][1] = pk_fma_ahi(c23, s23, C2[3][1]);
        }
        #pragma unroll
        for (int r = 0; r < 4; r++) {
            CS_[r][0] = C2[r][0].x; CS_[r][1] = C2[r][0].y;
            CS_[r][2] = C2[r][1].x; CS_[r][3] = C2[r][1].y;
        }
    }
    __syncthreads();  // B, C, Sin dead

    // exchange write: G -> Cy [k][257]; CS halves (x4<8) -> SinT [k][129]
    if (grp == 0) {
        #pragma unroll
        for (int k = 0; k < 16; k++) Cy[k * 257 + tg] = G_[k >> 2][k & 3];
    } else if (x4 < 8) {
        const int idx = t4 * 8 + x4;
        #pragma unroll
        for (int k = 0; k < 16; k++) SinT[k * 129 + idx] = CS_[k >> 2][k & 3];
    }
    __syncthreads();
    // exchange read
    if (grp == 1) {
        #pragma unroll
        for (int k = 0; k < 16; k++) G_[k >> 2][k & 3] = Cy[k * 257 + tg];
    } else if (x4 < 8) {
        const int idx = t4 * 8 + x4;
        #pragma unroll
        for (int k = 0; k < 16; k++) CS_[k >> 2][k & 3] = SinT[k * 129 + idx];
    }

    // phase E: proj z (cols 0..63) into Bz; WoN [16][65] into uW (R8 layout)
    for (int i = 0; i < 8; i++) {
        const int col = wv * 8 + i;
        float acc = pk_dot16(u2, Win + (size_t)(dir * 272 + col) * 16);
        Bz[XSW(col, lane)] = acc;
    }
    for (int j = tid; j < 1024; j += 512) {
        int c = j >> 6, d = j & 63;
        uW[c * 65 + d] = Wout[dir * 1024 + j] * normw[dir * 64 + d];
    }
    __syncthreads();  // all G/CS reads done; Cy becomes yv

    // phase F: group g handles heads 8g..8g+7; results -> yv. Packed inner.
    float* yv = Cy;  // [64 rows][4 p][17]
    const int tbase = 4 * t4;
    #pragma unroll 1
    for (int hh = 0; hh < 8; hh++) {
        const int h = 8 * grp + hh;
        const float* ctp = &ct2l[h * 68];
        const float* dtp = &dts[h * 68];
        float4 ctt4 = *(const float4*)&ctp[tbase];
        const float ctt[4] = {ctt4.x, ctt4.y, ctt4.z, ctt4.w};
        float4 cs4 = *(const float4*)&ctp[4 * x4];
        float4 dt4 = *(const float4*)&dtp[4 * x4];
        float4 xq[4];
        #pragma unroll
        for (int p = 0; p < 4; p++) {
            int m = 4 * h + p;
            xq[p] = *(const float4*)&xh_c[m * 64 + (((x4 ^ (m & 15)) & 15) << 2)];
        }
        f32x2 v2[2][4] = {};  // [r2][p] = {v[2*r2][p], v[2*r2+1][p]}
        #pragma unroll
        for (int q = 0; q < 4; q++) {
            const int s = 4 * x4 + q;
            float csq = (q == 0) ? cs4.x : (q == 1) ? cs4.y : (q == 2) ? cs4.z : cs4.w;
            float dtq = (q == 0) ? dt4.x : (q == 1) ? dt4.y : (q == 2) ? dt4.z : dt4.w;
            float w[4];
            #pragma unroll
            for (int r = 0; r < 4; r++) {
                float e = __builtin_amdgcn_exp2f(ctt[r] - csq);
                w[r] = (s <= tbase + r) ? (G_[r][q] * dtq) * e : 0.f;
            }
            f32x2 wp0 = {w[0], w[1]};
            f32x2 wp1 = {w[2], w[3]};
            #pragma unroll
            for (int p = 0; p < 4; p++) {
                f32x2 xpair = (q < 2) ? lo2(xq[p]) : hi2(xq[p]);
                if (q & 1) {
                    v2[0][p] = pk_fma_bhi(wp0, xpair, v2[0][p]);
                    v2[1][p] = pk_fma_bhi(wp1, xpair, v2[1][p]);
                } else {
                    v2[0][p] = pk_fma_blo(wp0, xpair, v2[0][p]);
                    v2[1][p] = pk_fma_blo(wp1, xpair, v2[1][p]);
                }
            }
        }
        if (x4 == h) {
            float ect[4];
            #pragma unroll
            for (int r = 0; r < 4; r++) ect[r] = __builtin_amdgcn_exp2f(ctt[r]);
            #pragma unroll
            for (int p = 0; p < 4; p++) {
                v2[0][p].x += ect[0] * CS_[0][p];
                v2[0][p].y += ect[1] * CS_[1][p];
                v2[1][p].x += ect[2] * CS_[2][p];
                v2[1][p].y += ect[3] * CS_[3][p];
            }
        }
        // unpack to logical v[4r+p]
        float v[16];
        #pragma unroll
        for (int p = 0; p < 4; p++) {
            v[p]      = v2[0][p].x;
            v[4 + p]  = v2[0][p].y;
            v[8 + p]  = v2[1][p].x;
            v[12 + p] = v2[1][p].y;
        }
        // butterfly reduce-scatter over 16 lanes: lane x4 ends with S[x4]
        #pragma unroll
        for (int j = 0; j < 8; j++) {
            float a = (x4 & 8) ? v[j + 8] : v[j];
            float s_ = (x4 & 8) ? v[j] : v[j + 8];
            v[j] = a + __shfl_xor(s_, 8);
        }
        #pragma unroll
        for (int j = 0; j < 4; j++) {
            float a = (x4 & 4) ? v[j + 4] : v[j];
            float s_ = (x4 & 4) ? v[j] : v[j + 4];
            v[j] = a + __shfl_xor(s_, 4);
        }
        #pragma unroll
        for (int j = 0; j < 2; j++) {
            float a = (x4 & 2) ? v[j + 2] : v[j];
            float s_ = (x4 & 2) ? v[j] : v[j + 2];
            v[j] = a + __shfl_xor(s_, 2);
        }
        {
            float a = (x4 & 1) ? v[1] : v[0];
            float s_ = (x4 & 1) ? v[0] : v[1];
            v[0] = a + __shfl_xor(s_, 1);
        }
        const int row = tbase + (x4 >> 2);
        yv[(row * 4 + (x4 & 3)) * 17 + h] = v[0];
    }
    __syncthreads();

    // phase G: epilogue on tid<256 (round-8 scalar form, WoN [16][65])
    float os[4];
    const int row = tid >> 2;
    const int p = tid & 3;
    if (tid < 256) {
        float gg[16], sumsq = 0.f;
        #pragma unroll
        for (int h = 0; h < 16; h++) {
            float yval = yv[(row * 4 + p) * 17 + h];
            int m = 4 * h + p;
            int ax = m * 64 + ((((row >> 2) ^ (m & 15)) & 15) << 2) + (row & 3);
            float xh = xh_c[ax];
            float zv = Bz[ax];
            float val = (yval + Dps[h] * xh) * fast_silu(zv);
            gg[h] = val;
            sumsq += val * val;
        }
        sumsq += __shfl_xor(sumsq, 1);
        sumsq += __shfl_xor(sumsq, 2);
        float rms = rsqrtf(sumsq * (1.f / 64.f) + 1e-5f);

        float oc[16];
        #pragma unroll
        for (int c = 0; c < 16; c++) {
            float a = 0.f;
            #pragma unroll
            for (int h = 0; h < 16; h++) a += gg[h] * uW[c * 65 + 4 * h + p];
            oc[c] = a;
        }
        #pragma unroll
        for (int c = 0; c < 16; c++) {
            oc[c] += __shfl_xor(oc[c], 1);
            oc[c] += __shfl_xor(oc[c], 2);
        }
        #pragma unroll
        for (int i2 = 0; i2 < 4; i2++) {
            float a0 = (p == 0) ? oc[i2] : oc[4 + i2];
            float a1 = (p == 2) ? oc[8 + i2] : oc[12 + i2];
            os[i2] = (((p & 2) == 0) ? a0 : a1) * rms;
        }
        size_t bl = (size_t)(b * 8192 + l0 + row);
        *(float4*)(ys + bl * 16 + 4 * p) = make_float4(os[0], os[1], os[2], os[3]);

        // BN partials
        float bs[4], bq[4];
        #pragma unroll
        for (int i2 = 0; i2 < 4; i2++) {
            float vv = fmaxf(os[i2], 0.f);
            bs[i2] = vv;
            bq[i2] = vv * vv;
        }
        #pragma unroll
        for (int off = 4; off < 64; off <<= 1) {
            #pragma unroll
            for (int i2 = 0; i2 < 4; i2++) {
                bs[i2] += __shfl_xor(bs[i2], off);
                bq[i2] += __shfl_xor(bq[i2], off);
            }
        }
        const int wlane = tid & 63, wvid = tid >> 6;
        if (wlane < 4) {
            #pragma unroll
            for (int i2 = 0; i2 < 4; i2++) {
                red[wvid][4 * wlane + i2] = bs[i2];
                red[wvid][16 + 4 * wlane + i2] = bq[i2];
            }
        }
    }
    __syncthreads();
    if (tid < 32) {
        float a = red[0][tid] + red[1][tid] + red[2][tid] + red[3][tid];
        partials[((size_t)(b * 128 + ck)) * 32 + tid] = a;
    }
}

// ---------------------------------------------------------------------------
// K_POOL_BN: reduce partials -> BN coefs, then BN + linear + maxpool(32).
// ---------------------------------------------------------------------------
__global__ __launch_bounds__(256) void k_pool_bn(
    const float* __restrict__ gamma, const float* __restrict__ beta,
    const float* __restrict__ lin_w, const float* __restrict__ lin_b,
    float* __restrict__ ws, float* __restrict__ out, int dir0, int dslm)
{
    float* base = ws + (size_t)(dslm * blockIdx.z) * PD;
    const float* ys = base + OFF_YS;
    const float* partials = base + OFF_PART;
    const int dir = dir0 + blockIdx.z;
    const int tid = threadIdx.x;
    __shared__ float red[8][33];
    __shared__ float cf[18];
    {
        int c = tid & 31, ks = tid >> 5;
        float a = 0.f;
        for (int k = ks * 128; k < ks * 128 + 128; k++) a += partials[k * 32 + c];
        red[ks][c] = a;
    }
    __syncthreads();
    if (tid < 32) {
        float a = 0.f;
        #pragma unroll
        for (int s2 = 1; s2 < 8; s2++) a += red[s2][tid];
        red[0][tid] += a;
    }
    __syncthreads();
    if (tid == 0) {
        float off = lin_b[dir];
        for (int c = 0; c < 16; c++) {
            float mu = red[0][c] * (1.f / 65536.f);
            float var = red[0][16 + c] * (1.f / 65536.f) - mu * mu;
            float inv = rsqrtf(var + 1e-5f);
            float coef = inv * gamma[dir * 16 + c] * lin_w[dir * 16 + c];
            cf[c] = coef;
            off += beta[dir * 16 + c] * lin_w[dir * 16 + c] - mu * coef;
        }
        cf[16] = off;
    }
    __syncthreads();

    const int b = blockIdx.x >> 3;
    const int jg = blockIdx.x & 7;
    const int j = jg * 32 + (tid >> 3);
    const int sub = tid & 7;
    float m = -3.4e38f;
    #pragma unroll
    for (int r = 0; r < 4; r++) {
        int l = j * PW + 8 * r + sub;
        const float* rowp = ys + (size_t)(b * 8192 + l) * 16;
        float sv = cf[16];
        #pragma unroll
        for (int k = 0; k < 4; k++) {
            float4 v4 = *(const float4*)(rowp + 4 * k);
            sv += fmaxf(v4.x, 0.f) * cf[4 * k] + fmaxf(v4.y, 0.f) * cf[4 * k + 1]
                + fmaxf(v4.z, 0.f) * cf[4 * k + 2] + fmaxf(v4.w, 0.f) * cf[4 * k + 3];
        }
        m = fmaxf(m, sv);
    }
    m = fmaxf(m, __shfl_xor(m, 1));
    m = fmaxf(m, __shfl_xor(m, 2));
    m = fmaxf(m, __shfl_xor(m, 4));
    if (sub == 0) out[b * 768 + dir * 256 + j] = m;
}

// ---------------------------------------------------------------------------
extern "C" void kernel_launch(void* const* d_in, const int* in_sizes, int n_in,
                              void* d_out, int out_size, void* d_ws, size_t ws_size,
                              hipStream_t stream) {
    const float* x     = (const float*)d_in[0];
    const float* Win   = (const float*)d_in[1];
    const float* convw = (const float*)d_in[2];
    const float* convb = (const float*)d_in[3];
    const float* dtb   = (const float*)d_in[4];
    const float* Alog  = (const float*)d_in[5];
    const float* Dp    = (const float*)d_in[6];
    const float* normw = (const float*)d_in[7];
    const float* Wout  = (const float*)d_in[8];
    const float* gamma = (const float*)d_in[9];
    const float* beta  = (const float*)d_in[10];
    const float* linw  = (const float*)d_in[11];
    const float* linb  = (const float*)d_in[12];
    float* out = (float*)d_out;
    float* ws = (float*)d_ws;

    const bool batched = ws_size >= (size_t)3 * PD * 4;
    const int nz = batched ? 3 : 1;
    const int dslm = batched ? 1 : 0;
    const int nloop = batched ? 1 : 3;

    for (int d0 = 0; d0 < nloop; ++d0) {
        k_delta<<<dim3(128, 8, nz), dim3(512), 0, stream>>>(
            x, Win, convw, convb, dtb, Alog, ws, d0, dslm);
        k_chunk_scan<<<dim3(512, 1, nz), dim3(64), 0, stream>>>(ws, dslm);
        k_out_epi<<<dim3(128, 8, nz), dim3(512), 0, stream>>>(
            x, Win, convw, convb, dtb, Alog, Dp, normw, Wout, ws, d0, dslm);
        k_pool_bn<<<dim3(64, 1, nz), dim3(256), 0, stream>>>(
            gamma, beta, linw, linb, ws, out, d0, dslm);
    }
}